// Round 3
// baseline (274.859 us; speedup 1.0000x reference)
//
#include <hip/hip_runtime.h>

#define F16 _Float16
typedef __attribute__((ext_vector_type(8))) _Float16 half8;
typedef __attribute__((ext_vector_type(4))) float f32x4;

constexpr int S = 2048;
constexpr int E = 2048;
constexpr float MASK_NEG = -66504.0f;
constexpr float INV_SQRT_D = 0.08838834764831845f;  // 1/sqrt(128)
constexpr float MASK_SC = MASK_NEG * INV_SQRT_D;    // mask applied to pre-scaled scores

__device__ __forceinline__ void gload16(const void* g, void* l) {
  __builtin_amdgcn_global_load_lds((const __attribute__((address_space(1))) void*)g,
                                   (__attribute__((address_space(3))) void*)l, 16, 0, 0);
}

// ---------------- elementwise f32 -> f16 cast ----------------
__global__ __launch_bounds__(256) void cast_f32_f16_k(const float* __restrict__ x,
                                                      F16* __restrict__ y) {
  size_t i = ((size_t)blockIdx.x * 256 + threadIdx.x) * 8;
  float4 a = *(const float4*)(x + i);
  float4 b = *(const float4*)(x + i + 4);
  half8 h;
  h[0] = (F16)a.x; h[1] = (F16)a.y; h[2] = (F16)a.z; h[3] = (F16)a.w;
  h[4] = (F16)b.x; h[5] = (F16)b.y; h[6] = (F16)b.z; h[7] = (F16)b.w;
  *(half8*)(y + i) = h;
}

// ---------------- dual f32 [E][E] -> f16 transposed [E][E] ----------------
__global__ __launch_bounds__(256) void transpose_cast2_k(const float* __restrict__ W0,
                                                         const float* __restrict__ W1,
                                                         F16* __restrict__ D0,
                                                         F16* __restrict__ D1) {
  const float* W = blockIdx.z ? W1 : W0;
  F16* Wt = blockIdx.z ? D1 : D0;
  __shared__ float tile[64][65];
  const int t = threadIdx.x;
  const int bx = blockIdx.x, by = blockIdx.y;
  {
    int r = t >> 4, c = (t & 15) << 2;
    const float* src = W + (size_t)(by * 64 + r) * E + bx * 64 + c;
    #pragma unroll
    for (int i = 0; i < 4; ++i) {
      float4 v = *(const float4*)(src + (size_t)i * 16 * E);
      tile[r + i * 16][c + 0] = v.x; tile[r + i * 16][c + 1] = v.y;
      tile[r + i * 16][c + 2] = v.z; tile[r + i * 16][c + 3] = v.w;
    }
  }
  __syncthreads();
  {
    int r = t >> 2, c = (t & 3) << 4;
    half8 v0, v1;
    #pragma unroll
    for (int i = 0; i < 8; ++i) v0[i] = (F16)tile[c + i][r];
    #pragma unroll
    for (int i = 0; i < 8; ++i) v1[i] = (F16)tile[c + 8 + i][r];
    F16* dst = Wt + (size_t)(bx * 64 + r) * E + by * 64 + c;
    *(half8*)dst = v0;
    *(half8*)(dst + 8) = v1;
  }
}

// ---------------- fp16 GEMM: C[M,N] = A[M,K] * Bt[N,K]^T ----------------
// MODE 0: single f16 out. MODE 1: fused QK (Bt has 4096 rows; bn<16 -> C0 scaled
// by 1/sqrt(D), else C1). MODE 2: f32 out.
template <int MODE>
__global__ __launch_bounds__(256, 2) void gemm_bt_k(const F16* __restrict__ A,
                                                    const F16* __restrict__ Bt,
                                                    void* __restrict__ C0v,
                                                    void* __restrict__ C1v) {
  constexpr int K = 2048, N = 2048;
  __shared__ F16 sA[128 * 64];
  __shared__ F16 sB[128 * 64];
  const int t = threadIdx.x;
  const int lane = t & 63, wave = t >> 6;
  const int wr = wave >> 1, wc = wave & 1;
  const int bm = blockIdx.y, bn = blockIdx.x;

  f32x4 acc[4][4];
  #pragma unroll
  for (int mi = 0; mi < 4; ++mi)
    #pragma unroll
    for (int ni = 0; ni < 4; ++ni) acc[mi][ni] = (f32x4){0.f, 0.f, 0.f, 0.f};

  const int rb = t >> 3;
  const int bofs = (t & 7) << 4;
  const int kOff = (bofs ^ ((rb & 7) << 4)) >> 1;
  const F16* aSrc = A + (size_t)(bm * 128 + rb) * K + kOff;
  const F16* bSrc = Bt + (size_t)(bn * 128 + rb) * K + kOff;
  F16* aDst = sA + t * 8;
  F16* bDst = sB + t * 8;

  for (int bk = 0; bk < K; bk += 64) {
    #pragma unroll
    for (int it = 0; it < 4; ++it) {
      gload16(aSrc + (size_t)it * 32 * K + bk, aDst + it * 2048);
      gload16(bSrc + (size_t)it * 32 * K + bk, bDst + it * 2048);
    }
    __syncthreads();
    #pragma unroll
    for (int kk = 0; kk < 2; ++kk) {
      half8 af[4], bf[4];
      const int kb = kk * 64 + ((lane >> 4) << 4);
      #pragma unroll
      for (int i = 0; i < 4; ++i) {
        const int ra = wr * 64 + i * 16 + (lane & 15);
        af[i] = *(const half8*)((const char*)sA + ra * 128 + (kb ^ ((ra & 7) << 4)));
        const int rn = wc * 64 + i * 16 + (lane & 15);
        bf[i] = *(const half8*)((const char*)sB + rn * 128 + (kb ^ ((rn & 7) << 4)));
      }
      #pragma unroll
      for (int mi = 0; mi < 4; ++mi)
        #pragma unroll
        for (int ni = 0; ni < 4; ++ni)
          acc[mi][ni] = __builtin_amdgcn_mfma_f32_16x16x32_f16(af[mi], bf[ni], acc[mi][ni], 0, 0, 0);
    }
    __syncthreads();
  }

  const float scale = (MODE == 1 && bn < 16) ? INV_SQRT_D : 1.0f;
  void* Cv = (MODE == 1 && bn >= 16) ? C1v : C0v;
  const int cb = (MODE == 1 ? (bn & 15) : bn) * 128;

  #pragma unroll
  for (int mi = 0; mi < 4; ++mi) {
    const int r0 = bm * 128 + wr * 64 + mi * 16 + ((lane >> 4) << 2);
    #pragma unroll
    for (int ni = 0; ni < 4; ++ni) {
      const int c = cb + wc * 64 + ni * 16 + (lane & 15);
      #pragma unroll
      for (int j = 0; j < 4; ++j) {
        if (MODE == 2)
          ((float*)Cv)[(size_t)(r0 + j) * N + c] = acc[mi][ni][j];
        else
          ((F16*)Cv)[(size_t)(r0 + j) * N + c] = (F16)(acc[mi][ni][j] * scale);
      }
    }
  }
}

// ---------------- flash attention (causal), KV-split waves ----------------
// Q pre-scaled. Q,K: [S,E] f16; Vt: [E,S] f16; O: [S,E] f16.
// Grid 1024 blocks x 256 thr. Block = 32 q rows of one head.
// Wave w: q-group (w&1)*16 rows, KV-split half (w>>1). K/V read direct from
// global (L2-resident); no barriers in main loop; merge via LDS at end.
__global__ __launch_bounds__(256, 4) void attn_fwd_k(const F16* __restrict__ Q,
                                                     const F16* __restrict__ Km,
                                                     const F16* __restrict__ Vt,
                                                     F16* __restrict__ O) {
  __shared__ float sO[2][16 * 132];  // hi-split unnormalized O (padded rows)
  __shared__ float sM[2][16], sL[2][16];
  __shared__ F16 sP[4][16 * 64];     // per-wave P, swizzled 128B rows
  const int t = threadIdx.x, lane = t & 63, w = t >> 6;
  const int h = blockIdx.x & 15;
  const int bq = blockIdx.x >> 4;          // 0..63
  const int quarter = bq >> 4, idx = bq & 15;
  // per-CU balanced qtile remap: blocks c,c+256,c+512,c+768 sum to 126
  const int qtile = (quarter == 0) ? idx
                  : (quarter == 1) ? 63 - idx
                  : (quarter == 2) ? 16 + idx
                                   : 47 - idx;
  const int qg = w & 1, split = w >> 1;
  const int qrow0 = qtile * 32 + qg * 16;
  const int nt = (qrow0 >> 6) + 1;         // causal kv-tile count for this q-group
  const int k0 = split ? (nt >> 1) : 0;
  const int k1 = split ? nt : (nt >> 1);

  half8 qf[4];
  {
    const F16* qp = Q + (size_t)(qrow0 + (lane & 15)) * E + h * 128 + ((lane >> 4) << 3);
    #pragma unroll
    for (int kd = 0; kd < 4; ++kd) qf[kd] = *(const half8*)(qp + kd * 32);
  }

  f32x4 oacc[8];
  #pragma unroll
  for (int i = 0; i < 8; ++i) oacc[i] = (f32x4){0.f, 0.f, 0.f, 0.f};
  float mrow[4] = {-3e38f, -3e38f, -3e38f, -3e38f};
  float lrow[4] = {0.f, 0.f, 0.f, 0.f};

  const F16* kBase = Km + (size_t)(lane & 15) * E + h * 128 + ((lane >> 4) << 3);
  const F16* vBase = Vt + ((size_t)h * 128 + (lane & 15)) * S + ((lane >> 4) << 3);
  F16* myP = (F16*)sP[w];

  for (int kt = k0; kt < k1; ++kt) {
    // ---- QK^T: 16 q rows x 64 kv, B-fragments direct from global ----
    f32x4 sacc[4];
    #pragma unroll
    for (int i = 0; i < 4; ++i) sacc[i] = (f32x4){0.f, 0.f, 0.f, 0.f};
    __builtin_amdgcn_s_setprio(1);
    #pragma unroll
    for (int kd = 0; kd < 4; ++kd) {
      #pragma unroll
      for (int ni = 0; ni < 4; ++ni) {
        half8 bf = *(const half8*)(kBase + ((size_t)kt * 64 + ni * 16) * E + kd * 32);
        sacc[ni] = __builtin_amdgcn_mfma_f32_16x16x32_f16(qf[kd], bf, sacc[ni], 0, 0, 0);
      }
    }
    __builtin_amdgcn_s_setprio(0);

    const bool diag = (kt == nt - 1);
    const int qg0 = qrow0 + ((lane >> 4) << 2);
    const int kg0 = kt * 64 + (lane & 15);
    #pragma unroll
    for (int j = 0; j < 4; ++j) {
      float mx = -3e38f;
      #pragma unroll
      for (int ni = 0; ni < 4; ++ni) {
        float s = sacc[ni][j];
        if (diag && (kg0 + ni * 16) > (qg0 + j)) s += MASK_SC;
        sacc[ni][j] = s;
        mx = fmaxf(mx, s);
      }
      mx = fmaxf(mx, __shfl_xor(mx, 1));
      mx = fmaxf(mx, __shfl_xor(mx, 2));
      mx = fmaxf(mx, __shfl_xor(mx, 4));
      mx = fmaxf(mx, __shfl_xor(mx, 8));
      const float mnew = fmaxf(mrow[j], mx);
      const float sc = __expf(mrow[j] - mnew);
      float rs = 0.f;
      #pragma unroll
      for (int ni = 0; ni < 4; ++ni) {
        const float p = __expf(sacc[ni][j] - mnew);
        sacc[ni][j] = p;
        rs += p;
      }
      rs += __shfl_xor(rs, 1);
      rs += __shfl_xor(rs, 2);
      rs += __shfl_xor(rs, 4);
      rs += __shfl_xor(rs, 8);
      lrow[j] = lrow[j] * sc + rs;
      mrow[j] = mnew;
      #pragma unroll
      for (int df = 0; df < 8; ++df) oacc[df][j] *= sc;
    }

    // ---- P (f16) -> wave-private LDS, swizzled ----
    {
      const int rl0 = (lane >> 4) << 2;
      #pragma unroll
      for (int ni = 0; ni < 4; ++ni) {
        const int cb = (ni * 16 + (lane & 15)) * 2;
        #pragma unroll
        for (int j = 0; j < 4; ++j) {
          const int r = rl0 + j;
          *(F16*)((char*)myP + r * 128 + (cb ^ ((r & 7) << 4))) = (F16)sacc[ni][j];
        }
      }
    }

    // ---- PV: V-fragments direct from global ----
    __builtin_amdgcn_s_setprio(1);
    #pragma unroll
    for (int kk = 0; kk < 2; ++kk) {
      const int kb = kk * 64 + ((lane >> 4) << 4);
      const int ra = lane & 15;
      half8 pa = *(const half8*)((const char*)myP + ra * 128 + (kb ^ ((ra & 7) << 4)));
      #pragma unroll
      for (int df = 0; df < 8; ++df) {
        half8 vf = *(const half8*)(vBase + (size_t)df * 16 * S + kt * 64 + kk * 32);
        oacc[df] = __builtin_amdgcn_mfma_f32_16x16x32_f16(pa, vf, oacc[df], 0, 0, 0);
      }
    }
    __builtin_amdgcn_s_setprio(0);
  }

  // ---- merge lo/hi splits ----
  const int r0 = (lane >> 4) << 2;
  if (w >= 2) {
    float* ob = sO[w - 2];
    #pragma unroll
    for (int j = 0; j < 4; ++j) {
      #pragma unroll
      for (int df = 0; df < 8; ++df)
        ob[(r0 + j) * 132 + df * 16 + (lane & 15)] = oacc[df][j];
      if ((lane & 15) == 0) { sM[w - 2][r0 + j] = mrow[j]; sL[w - 2][r0 + j] = lrow[j]; }
    }
  }
  __syncthreads();
  if (w < 2) {
    const float* ob = sO[w];
    #pragma unroll
    for (int j = 0; j < 4; ++j) {
      const float m2 = sM[w][r0 + j], l2 = sL[w][r0 + j];
      const float mn = fmaxf(mrow[j], m2);
      const float a1 = __expf(mrow[j] - mn), a2 = __expf(m2 - mn);
      const float inv = 1.0f / (lrow[j] * a1 + l2 * a2);
      F16* op = O + (size_t)(qrow0 + r0 + j) * E + h * 128 + (lane & 15);
      #pragma unroll
      for (int df = 0; df < 8; ++df) {
        const float v = (oacc[df][j] * a1 + ob[(r0 + j) * 132 + df * 16 + (lane & 15)] * a2) * inv;
        op[df * 16] = (F16)v;
      }
    }
  }
}

// ---------------- launcher ----------------
extern "C" void kernel_launch(void* const* d_in, const int* in_sizes, int n_in,
                              void* d_out, int out_size, void* d_ws, size_t ws_size,
                              hipStream_t stream) {
  const float* X  = (const float*)d_in[0];
  const float* Wq = (const float*)d_in[1];
  const float* Wk = (const float*)d_in[2];
  const float* Wv = (const float*)d_in[3];
  const float* Wo = (const float*)d_in[4];
  float* out = (float*)d_out;

  const size_t MAT = (size_t)2048 * 2048;
  F16* Xh  = (F16*)d_ws;     // X f16 [S,E]; later reused as attn output Ah
  F16* Wt0 = Xh + MAT;       // Wq^T, then Wv^T
  F16* Wt1 = Wt0 + MAT;      // Wk^T, then Wo^T
  F16* Qh  = Wt1 + MAT;      // Q (pre-scaled by 1/sqrt(D))
  F16* Kh  = Qh + MAT;       // K
  F16* Vh  = Kh + MAT;       // V^T [E,S]
  // workspace: 6 * 8 MiB = 48 MiB

  dim3 b256(256);
  cast_f32_f16_k<<<dim3(MAT / 2048), b256, 0, stream>>>(X, Xh);

  transpose_cast2_k<<<dim3(32, 32, 2), b256, 0, stream>>>(Wq, Wk, Wt0, Wt1);
  gemm_bt_k<1><<<dim3(32, 16), b256, 0, stream>>>(Xh, Wt0, Qh, Kh);   // Q (scaled), K

  transpose_cast2_k<<<dim3(32, 32, 2), b256, 0, stream>>>(Wv, Wo, Wt0, Wt1);
  gemm_bt_k<0><<<dim3(16, 16), b256, 0, stream>>>(Wt0, Xh, Vh, nullptr);  // V^T = Wv^T X^T

  attn_fwd_k<<<dim3(1024), b256, 0, stream>>>(Qh, Kh, Vh, Xh);  // attn out -> Xh

  gemm_bt_k<2><<<dim3(16, 16), b256, 0, stream>>>(Xh, Wt1, out, nullptr);
}

// Round 4
// 195.082 us; speedup vs baseline: 1.4089x; 1.4089x over previous
//
#include <hip/hip_runtime.h>

#define F16 _Float16
typedef __attribute__((ext_vector_type(8))) _Float16 half8;
typedef __attribute__((ext_vector_type(4))) float f32x4;

constexpr int S = 2048;
constexpr int E = 2048;
constexpr float MASK_NEG = -66504.0f;
constexpr float INV_SQRT_D = 0.08838834764831845f;  // 1/sqrt(128)
constexpr float MASK_SC = MASK_NEG * INV_SQRT_D;    // mask applied to pre-scaled scores

__device__ __forceinline__ void gload16(const void* g, void* l) {
  __builtin_amdgcn_global_load_lds((const __attribute__((address_space(1))) void*)g,
                                   (__attribute__((address_space(3))) void*)l, 16, 0, 0);
}

// ---------------- elementwise f32 -> f16 cast ----------------
__global__ __launch_bounds__(256) void cast_f32_f16_k(const float* __restrict__ x,
                                                      F16* __restrict__ y) {
  size_t i = ((size_t)blockIdx.x * 256 + threadIdx.x) * 8;
  float4 a = *(const float4*)(x + i);
  float4 b = *(const float4*)(x + i + 4);
  half8 h;
  h[0] = (F16)a.x; h[1] = (F16)a.y; h[2] = (F16)a.z; h[3] = (F16)a.w;
  h[4] = (F16)b.x; h[5] = (F16)b.y; h[6] = (F16)b.z; h[7] = (F16)b.w;
  *(half8*)(y + i) = h;
}

// ---------------- dual f32 [E][E] -> f16 transposed [E][E] ----------------
__global__ __launch_bounds__(256) void transpose_cast2_k(const float* __restrict__ W0,
                                                         const float* __restrict__ W1,
                                                         F16* __restrict__ D0,
                                                         F16* __restrict__ D1) {
  const float* W = blockIdx.z ? W1 : W0;
  F16* Wt = blockIdx.z ? D1 : D0;
  __shared__ float tile[64][65];
  const int t = threadIdx.x;
  const int bx = blockIdx.x, by = blockIdx.y;
  {
    int r = t >> 4, c = (t & 15) << 2;
    const float* src = W + (size_t)(by * 64 + r) * E + bx * 64 + c;
    #pragma unroll
    for (int i = 0; i < 4; ++i) {
      float4 v = *(const float4*)(src + (size_t)i * 16 * E);
      tile[r + i * 16][c + 0] = v.x; tile[r + i * 16][c + 1] = v.y;
      tile[r + i * 16][c + 2] = v.z; tile[r + i * 16][c + 3] = v.w;
    }
  }
  __syncthreads();
  {
    int r = t >> 2, c = (t & 3) << 4;
    half8 v0, v1;
    #pragma unroll
    for (int i = 0; i < 8; ++i) v0[i] = (F16)tile[c + i][r];
    #pragma unroll
    for (int i = 0; i < 8; ++i) v1[i] = (F16)tile[c + 8 + i][r];
    F16* dst = Wt + (size_t)(bx * 64 + r) * E + by * 64 + c;
    *(half8*)dst = v0;
    *(half8*)(dst + 8) = v1;
  }
}

// ---------------- fp16 GEMM: C[M,N] = A[M,K] * Bt[N,K]^T ----------------
// Tile 64(M) x 128(N), BK=64, 4 waves (2Mx2N). Grid (N/128, M/64).
// MODE 0: single f16 out. MODE 1: fused QK (Bt 4096 rows; bn<16 -> C0 scaled
// by 1/sqrt(D), else C1). MODE 2: f32 out.
template <int MODE>
__global__ __launch_bounds__(256, 2) void gemm_bt_k(const F16* __restrict__ A,
                                                    const F16* __restrict__ Bt,
                                                    void* __restrict__ C0v,
                                                    void* __restrict__ C1v) {
  constexpr int K = 2048, N = 2048;
  __shared__ F16 sA[64 * 64];
  __shared__ F16 sB[128 * 64];
  const int t = threadIdx.x;
  const int lane = t & 63, wave = t >> 6;
  const int wr = wave >> 1, wc = wave & 1;
  const int bm = blockIdx.y, bn = blockIdx.x;

  f32x4 acc[2][4];
  #pragma unroll
  for (int mi = 0; mi < 2; ++mi)
    #pragma unroll
    for (int ni = 0; ni < 4; ++ni) acc[mi][ni] = (f32x4){0.f, 0.f, 0.f, 0.f};

  const int rb = t >> 3;                     // 0..31
  const int bofs = (t & 7) << 4;
  const int kOff = (bofs ^ ((rb & 7) << 4)) >> 1;
  const F16* aSrc = A + (size_t)(bm * 64 + rb) * K + kOff;
  const F16* bSrc = Bt + (size_t)(bn * 128 + rb) * K + kOff;
  F16* aDst = sA + t * 8;
  F16* bDst = sB + t * 8;

  for (int bk = 0; bk < K; bk += 64) {
    #pragma unroll
    for (int it = 0; it < 2; ++it)
      gload16(aSrc + (size_t)it * 32 * K + bk, aDst + it * 2048);
    #pragma unroll
    for (int it = 0; it < 4; ++it)
      gload16(bSrc + (size_t)it * 32 * K + bk, bDst + it * 2048);
    __syncthreads();
    #pragma unroll
    for (int kk = 0; kk < 2; ++kk) {
      half8 af[2], bf[4];
      const int kb = kk * 64 + ((lane >> 4) << 4);
      #pragma unroll
      for (int i = 0; i < 2; ++i) {
        const int ra = wr * 32 + i * 16 + (lane & 15);
        af[i] = *(const half8*)((const char*)sA + ra * 128 + (kb ^ ((ra & 7) << 4)));
      }
      #pragma unroll
      for (int i = 0; i < 4; ++i) {
        const int rn = wc * 64 + i * 16 + (lane & 15);
        bf[i] = *(const half8*)((const char*)sB + rn * 128 + (kb ^ ((rn & 7) << 4)));
      }
      #pragma unroll
      for (int mi = 0; mi < 2; ++mi)
        #pragma unroll
        for (int ni = 0; ni < 4; ++ni)
          acc[mi][ni] = __builtin_amdgcn_mfma_f32_16x16x32_f16(af[mi], bf[ni], acc[mi][ni], 0, 0, 0);
    }
    __syncthreads();
  }

  const float scale = (MODE == 1 && bn < 16) ? INV_SQRT_D : 1.0f;
  void* Cv = (MODE == 1 && bn >= 16) ? C1v : C0v;
  const int cb = (MODE == 1 ? (bn & 15) : bn) * 128;

  #pragma unroll
  for (int mi = 0; mi < 2; ++mi) {
    const int r0 = bm * 64 + wr * 32 + mi * 16 + ((lane >> 4) << 2);
    #pragma unroll
    for (int ni = 0; ni < 4; ++ni) {
      const int c = cb + wc * 64 + ni * 16 + (lane & 15);
      #pragma unroll
      for (int j = 0; j < 4; ++j) {
        if (MODE == 2)
          ((float*)Cv)[(size_t)(r0 + j) * N + c] = acc[mi][ni][j];
        else
          ((F16*)Cv)[(size_t)(r0 + j) * N + c] = (F16)(acc[mi][ni][j] * scale);
      }
    }
  }
}

// ---------------- flash attention (causal) ----------------
// Q pre-scaled by 1/sqrt(D). Q,K: [S,E] f16; Vt: [E,S] f16; O: [S,E] f16.
// 512 blocks, 4 waves x 16 q rows. LDS-staged dbuf K/V, 1 barrier/iter.
// Co-resident pair (c, c+256) has constant work sum 31+2 units.
__global__ __launch_bounds__(256, 2) void attn_fwd_k(const F16* __restrict__ Q,
                                                     const F16* __restrict__ Km,
                                                     const F16* __restrict__ Vt,
                                                     F16* __restrict__ O) {
  __shared__ F16 sK[2][64 * 128];  // [kv][d], 256B rows, swz (r&15)<<4
  __shared__ F16 sV[2][128 * 64];  // [d][kv], 128B rows, swz (r&7)<<4
  __shared__ F16 sP[4][16 * 64];   // per-wave P, swizzled 128B rows
  const int t = threadIdx.x, lane = t & 63, w = t >> 6;
  const int h = blockIdx.x & 15;
  const int bq = blockIdx.x >> 4;  // 0..31
  const int qt = (bq < 16) ? (31 - bq) : (bq - 16);  // pair-sum = 31
  const int qrow0 = qt * 64 + w * 16;

  half8 qf[4];
  {
    const int r = qrow0 + (lane & 15);
    const F16* qp = Q + (size_t)r * E + h * 128 + ((lane >> 4) << 3);
    #pragma unroll
    for (int kd = 0; kd < 4; ++kd) qf[kd] = *(const half8*)(qp + kd * 32);
  }

  f32x4 oacc[8];
  #pragma unroll
  for (int i = 0; i < 8; ++i) oacc[i] = (f32x4){0.f, 0.f, 0.f, 0.f};
  float mrow[4] = {-3e38f, -3e38f, -3e38f, -3e38f};
  float lrow[4] = {0.f, 0.f, 0.f, 0.f};

  const int rk = t >> 4;
  const int kcol = (((t & 15) << 4) ^ ((rk & 15) << 4)) >> 1;  // d offset (elems)
  const int rv = t >> 3;
  const int vcol = (((t & 7) << 4) ^ ((rv & 7) << 4)) >> 1;    // kv offset (elems)
  const F16* kBase = Km + (size_t)rk * E + h * 128 + kcol;
  const F16* vBase = Vt + (size_t)(h * 128 + rv) * S + vcol;
  F16* myP = (F16*)sP[w];

  auto stage = [&](int kt, int b) {
    const F16* kSrc = kBase + (size_t)kt * 64 * E;
    const F16* vSrc = vBase + kt * 64;
    #pragma unroll
    for (int it = 0; it < 4; ++it) {
      gload16(kSrc + (size_t)it * 16 * E, &sK[b][t * 8 + it * 2048]);
      gload16(vSrc + (size_t)it * 32 * S, &sV[b][t * 8 + it * 2048]);
    }
  };

  stage(0, 0);
  const int nt = qt + 1;

  for (int kt = 0; kt < nt; ++kt) {
    __syncthreads();  // tile kt landed; all waves done with buf being overwritten
    if (kt + 1 < nt) stage(kt + 1, (kt + 1) & 1);
    const char* bK = (const char*)sK[kt & 1];
    const char* bV = (const char*)sV[kt & 1];

    // ---- QK^T: wave's 16 q rows x 64 kv (Q pre-scaled) ----
    f32x4 sacc[4];
    #pragma unroll
    for (int i = 0; i < 4; ++i) sacc[i] = (f32x4){0.f, 0.f, 0.f, 0.f};
    __builtin_amdgcn_s_setprio(1);
    #pragma unroll
    for (int kd = 0; kd < 4; ++kd) {
      const int kb = kd * 64 + ((lane >> 4) << 4);
      #pragma unroll
      for (int ni = 0; ni < 4; ++ni) {
        const int rn = ni * 16 + (lane & 15);
        half8 bf = *(const half8*)(bK + rn * 256 + (kb ^ ((rn & 15) << 4)));
        sacc[ni] = __builtin_amdgcn_mfma_f32_16x16x32_f16(qf[kd], bf, sacc[ni], 0, 0, 0);
      }
    }
    __builtin_amdgcn_s_setprio(0);

    // ---- online softmax with defer-max (THR=8) ----
    const bool diag = (kt == nt - 1);
    const int qg0 = qrow0 + ((lane >> 4) << 2);
    const int kg0 = kt * 64 + (lane & 15);
    float mxs[4];
    bool need = false;
    #pragma unroll
    for (int j = 0; j < 4; ++j) {
      float mx = -3e38f;
      #pragma unroll
      for (int ni = 0; ni < 4; ++ni) {
        float s = sacc[ni][j];
        if (diag && (kg0 + ni * 16) > (qg0 + j)) s += MASK_SC;
        sacc[ni][j] = s;
        mx = fmaxf(mx, s);
      }
      mx = fmaxf(mx, __shfl_xor(mx, 1));
      mx = fmaxf(mx, __shfl_xor(mx, 2));
      mx = fmaxf(mx, __shfl_xor(mx, 4));
      mx = fmaxf(mx, __shfl_xor(mx, 8));
      mxs[j] = mx;
      need = need || (mx > mrow[j] + 8.0f);
    }
    if (__any(need)) {
      #pragma unroll
      for (int j = 0; j < 4; ++j) {
        const float mnew = fmaxf(mrow[j], mxs[j]);
        const float sc = __expf(mrow[j] - mnew);
        float rs = 0.f;
        #pragma unroll
        for (int ni = 0; ni < 4; ++ni) {
          const float p = __expf(sacc[ni][j] - mnew);
          sacc[ni][j] = p;
          rs += p;
        }
        rs += __shfl_xor(rs, 1);
        rs += __shfl_xor(rs, 2);
        rs += __shfl_xor(rs, 4);
        rs += __shfl_xor(rs, 8);
        lrow[j] = lrow[j] * sc + rs;
        mrow[j] = mnew;
        #pragma unroll
        for (int df = 0; df < 8; ++df) oacc[df][j] *= sc;
      }
    } else {
      #pragma unroll
      for (int j = 0; j < 4; ++j) {
        float rs = 0.f;
        #pragma unroll
        for (int ni = 0; ni < 4; ++ni) {
          const float p = __expf(sacc[ni][j] - mrow[j]);  // bounded by e^8
          sacc[ni][j] = p;
          rs += p;
        }
        rs += __shfl_xor(rs, 1);
        rs += __shfl_xor(rs, 2);
        rs += __shfl_xor(rs, 4);
        rs += __shfl_xor(rs, 8);
        lrow[j] += rs;
      }
    }

    // ---- P (f16) -> wave-private LDS, swizzled ----
    {
      const int rl0 = (lane >> 4) << 2;
      #pragma unroll
      for (int ni = 0; ni < 4; ++ni) {
        const int cb = (ni * 16 + (lane & 15)) * 2;
        #pragma unroll
        for (int j = 0; j < 4; ++j) {
          const int r = rl0 + j;
          *(F16*)((char*)myP + r * 128 + (cb ^ ((r & 7) << 4))) = (F16)sacc[ni][j];
        }
      }
    }

    // ---- PV: oacc += P * V ----
    __builtin_amdgcn_s_setprio(1);
    #pragma unroll
    for (int kk = 0; kk < 2; ++kk) {
      const int kb = kk * 64 + ((lane >> 4) << 4);
      const int ra = lane & 15;
      half8 pa = *(const half8*)((const char*)myP + ra * 128 + (kb ^ ((ra & 7) << 4)));
      #pragma unroll
      for (int df = 0; df < 8; ++df) {
        const int rd = df * 16 + (lane & 15);
        half8 vf = *(const half8*)(bV + rd * 128 + (kb ^ ((rd & 7) << 4)));
        oacc[df] = __builtin_amdgcn_mfma_f32_16x16x32_f16(pa, vf, oacc[df], 0, 0, 0);
      }
    }
    __builtin_amdgcn_s_setprio(0);
  }

  #pragma unroll
  for (int j = 0; j < 4; ++j) {
    const float inv = 1.0f / lrow[j];
    const int r = qrow0 + ((lane >> 4) << 2) + j;
    F16* op = O + (size_t)r * E + h * 128 + (lane & 15);
    #pragma unroll
    for (int df = 0; df < 8; ++df) op[df * 16] = (F16)(oacc[df][j] * inv);
  }
}

// ---------------- launcher ----------------
extern "C" void kernel_launch(void* const* d_in, const int* in_sizes, int n_in,
                              void* d_out, int out_size, void* d_ws, size_t ws_size,
                              hipStream_t stream) {
  const float* X  = (const float*)d_in[0];
  const float* Wq = (const float*)d_in[1];
  const float* Wk = (const float*)d_in[2];
  const float* Wv = (const float*)d_in[3];
  const float* Wo = (const float*)d_in[4];
  float* out = (float*)d_out;

  const size_t MAT = (size_t)2048 * 2048;
  F16* Xh  = (F16*)d_ws;     // X f16 [S,E]; later reused as attn output Ah
  F16* Wt0 = Xh + MAT;       // Wq^T, then Wv^T
  F16* Wt1 = Wt0 + MAT;      // Wk^T, then Wo^T
  F16* Qh  = Wt1 + MAT;      // Q (pre-scaled by 1/sqrt(D))
  F16* Kh  = Qh + MAT;       // K
  F16* Vh  = Kh + MAT;       // V^T [E,S]
  // workspace: 6 * 8 MiB = 48 MiB

  dim3 b256(256);
  cast_f32_f16_k<<<dim3(MAT / 2048), b256, 0, stream>>>(X, Xh);

  transpose_cast2_k<<<dim3(32, 32, 2), b256, 0, stream>>>(Wq, Wk, Wt0, Wt1);
  gemm_bt_k<1><<<dim3(32, 32), b256, 0, stream>>>(Xh, Wt0, Qh, Kh);   // Q (scaled), K

  transpose_cast2_k<<<dim3(32, 32, 2), b256, 0, stream>>>(Wv, Wo, Wt0, Wt1);
  gemm_bt_k<0><<<dim3(16, 32), b256, 0, stream>>>(Wt0, Xh, Vh, nullptr);  // V^T = Wv^T X^T

  attn_fwd_k<<<dim3(512), b256, 0, stream>>>(Qh, Kh, Vh, Xh);  // attn out -> Xh

  gemm_bt_k<2><<<dim3(16, 32), b256, 0, stream>>>(Xh, Wt1, out, nullptr);
}

// Round 5
// 178.948 us; speedup vs baseline: 1.5360x; 1.0902x over previous
//
#include <hip/hip_runtime.h>

#define F16 _Float16
typedef __attribute__((ext_vector_type(8))) _Float16 half8;
typedef __attribute__((ext_vector_type(4))) _Float16 half4;
typedef __attribute__((ext_vector_type(4))) float f32x4;

constexpr int S = 2048;
constexpr int E = 2048;
constexpr float MASK_NEG = -66504.0f;
constexpr float INV_SQRT_D = 0.08838834764831845f;  // 1/sqrt(128)
constexpr float MASK_SC = MASK_NEG * INV_SQRT_D;    // mask applied to pre-scaled scores

__device__ __forceinline__ void gload16(const void* g, void* l) {
  __builtin_amdgcn_global_load_lds((const __attribute__((address_space(1))) void*)g,
                                   (__attribute__((address_space(3))) void*)l, 16, 0, 0);
}

// ---------------- elementwise f32 -> f16 cast ----------------
__global__ __launch_bounds__(256) void cast_f32_f16_k(const float* __restrict__ x,
                                                      F16* __restrict__ y) {
  size_t i = ((size_t)blockIdx.x * 256 + threadIdx.x) * 8;
  float4 a = *(const float4*)(x + i);
  float4 b = *(const float4*)(x + i + 4);
  half8 h;
  h[0] = (F16)a.x; h[1] = (F16)a.y; h[2] = (F16)a.z; h[3] = (F16)a.w;
  h[4] = (F16)b.x; h[5] = (F16)b.y; h[6] = (F16)b.z; h[7] = (F16)b.w;
  *(half8*)(y + i) = h;
}

// ---------------- dual f32 [E][E] -> f16 transposed [E][E] ----------------
__global__ __launch_bounds__(256) void transpose_cast2_k(const float* __restrict__ W0,
                                                         const float* __restrict__ W1,
                                                         F16* __restrict__ D0,
                                                         F16* __restrict__ D1) {
  const float* W = blockIdx.z ? W1 : W0;
  F16* Wt = blockIdx.z ? D1 : D0;
  __shared__ float tile[64][65];
  const int t = threadIdx.x;
  const int bx = blockIdx.x, by = blockIdx.y;
  {
    int r = t >> 4, c = (t & 15) << 2;
    const float* src = W + (size_t)(by * 64 + r) * E + bx * 64 + c;
    #pragma unroll
    for (int i = 0; i < 4; ++i) {
      float4 v = *(const float4*)(src + (size_t)i * 16 * E);
      tile[r + i * 16][c + 0] = v.x; tile[r + i * 16][c + 1] = v.y;
      tile[r + i * 16][c + 2] = v.z; tile[r + i * 16][c + 3] = v.w;
    }
  }
  __syncthreads();
  {
    int r = t >> 2, c = (t & 3) << 4;
    half8 v0, v1;
    #pragma unroll
    for (int i = 0; i < 8; ++i) v0[i] = (F16)tile[c + i][r];
    #pragma unroll
    for (int i = 0; i < 8; ++i) v1[i] = (F16)tile[c + 8 + i][r];
    F16* dst = Wt + (size_t)(bx * 64 + r) * E + by * 64 + c;
    *(half8*)dst = v0;
    *(half8*)(dst + 8) = v1;
  }
}

// ---------------- fp16 GEMM: C[M,N] = A[M,K] * Bt[N,K]^T ----------------
// Tile 64(M) x 128(N), BK=64, 4 waves (2Mx2N). Grid (N/128, M/64).
// MODE 0: single f16 out. MODE 1: fused QK (Bt 4096 rows; bn<16 -> C0 scaled
// by 1/sqrt(D), else C1). MODE 2: f32 out.
template <int MODE>
__global__ __launch_bounds__(256, 2) void gemm_bt_k(const F16* __restrict__ A,
                                                    const F16* __restrict__ Bt,
                                                    void* __restrict__ C0v,
                                                    void* __restrict__ C1v) {
  constexpr int K = 2048, N = 2048;
  __shared__ F16 sA[64 * 64];
  __shared__ F16 sB[128 * 64];
  const int t = threadIdx.x;
  const int lane = t & 63, wave = t >> 6;
  const int wr = wave >> 1, wc = wave & 1;
  const int bm = blockIdx.y, bn = blockIdx.x;

  f32x4 acc[2][4];
  #pragma unroll
  for (int mi = 0; mi < 2; ++mi)
    #pragma unroll
    for (int ni = 0; ni < 4; ++ni) acc[mi][ni] = (f32x4){0.f, 0.f, 0.f, 0.f};

  const int rb = t >> 3;                     // 0..31
  const int bofs = (t & 7) << 4;
  const int kOff = (bofs ^ ((rb & 7) << 4)) >> 1;
  const F16* aSrc = A + (size_t)(bm * 64 + rb) * K + kOff;
  const F16* bSrc = Bt + (size_t)(bn * 128 + rb) * K + kOff;
  F16* aDst = sA + t * 8;
  F16* bDst = sB + t * 8;

  for (int bk = 0; bk < K; bk += 64) {
    #pragma unroll
    for (int it = 0; it < 2; ++it)
      gload16(aSrc + (size_t)it * 32 * K + bk, aDst + it * 2048);
    #pragma unroll
    for (int it = 0; it < 4; ++it)
      gload16(bSrc + (size_t)it * 32 * K + bk, bDst + it * 2048);
    __syncthreads();
    #pragma unroll
    for (int kk = 0; kk < 2; ++kk) {
      half8 af[2], bf[4];
      const int kb = kk * 64 + ((lane >> 4) << 4);
      #pragma unroll
      for (int i = 0; i < 2; ++i) {
        const int ra = wr * 32 + i * 16 + (lane & 15);
        af[i] = *(const half8*)((const char*)sA + ra * 128 + (kb ^ ((ra & 7) << 4)));
      }
      #pragma unroll
      for (int i = 0; i < 4; ++i) {
        const int rn = wc * 64 + i * 16 + (lane & 15);
        bf[i] = *(const half8*)((const char*)sB + rn * 128 + (kb ^ ((rn & 7) << 4)));
      }
      #pragma unroll
      for (int mi = 0; mi < 2; ++mi)
        #pragma unroll
        for (int ni = 0; ni < 4; ++ni)
          acc[mi][ni] = __builtin_amdgcn_mfma_f32_16x16x32_f16(af[mi], bf[ni], acc[mi][ni], 0, 0, 0);
    }
    __syncthreads();
  }

  const float scale = (MODE == 1 && bn < 16) ? INV_SQRT_D : 1.0f;
  void* Cv = (MODE == 1 && bn >= 16) ? C1v : C0v;
  const int cb = (MODE == 1 ? (bn & 15) : bn) * 128;

  #pragma unroll
  for (int mi = 0; mi < 2; ++mi) {
    const int r0 = bm * 64 + wr * 32 + mi * 16 + ((lane >> 4) << 2);
    #pragma unroll
    for (int ni = 0; ni < 4; ++ni) {
      const int c = cb + wc * 64 + ni * 16 + (lane & 15);
      #pragma unroll
      for (int j = 0; j < 4; ++j) {
        if (MODE == 2)
          ((float*)Cv)[(size_t)(r0 + j) * N + c] = acc[mi][ni][j];
        else
          ((F16*)Cv)[(size_t)(r0 + j) * N + c] = (F16)(acc[mi][ni][j] * scale);
      }
    }
  }
}

// ---------------- flash attention (causal), swapped-operand QK^T ----------------
// Q pre-scaled by 1/sqrt(D). Q,K: [S,E] f16; Vt: [E,S] f16; O: [S,E] f16.
// 512 blocks, 4 waves x 16 q rows. LDS-staged dbuf K/V, 1 barrier/iter.
// mfma(K,Q) -> lane holds S^T column: ONE q (lane&15), 16 kv values in regs.
// Row-softmax = 15 in-lane fmax + 2 shfl (vs 32 shfl before).
__global__ __launch_bounds__(256, 2) void attn_fwd_k(const F16* __restrict__ Q,
                                                     const F16* __restrict__ Km,
                                                     const F16* __restrict__ Vt,
                                                     F16* __restrict__ O) {
  __shared__ F16 sK[2][64 * 128];  // [kv][d], 256B rows, swz (r&15)<<4
  __shared__ F16 sV[2][128 * 64];  // [d][kv], 128B rows, swz (r&7)<<4
  __shared__ F16 sP[4][16 * 64];   // per-wave P [q][kv], swz (r&7)<<4
  const int t = threadIdx.x, lane = t & 63, w = t >> 6;
  const int h = blockIdx.x & 15;
  const int bq = blockIdx.x >> 4;  // 0..31
  const int qt = (bq < 16) ? (31 - bq) : (bq - 16);  // co-resident pair-sum = 31
  const int qrow0 = qt * 64 + w * 16;
  const int g = lane >> 4;         // 4-lane k-slice group
  const int myq = qrow0 + (lane & 15);

  half8 qf[4];
  {
    const F16* qp = Q + (size_t)myq * E + h * 128 + (g << 3);
    #pragma unroll
    for (int kd = 0; kd < 4; ++kd) qf[kd] = *(const half8*)(qp + kd * 32);
  }

  f32x4 oacc[8];  // O^T: oacc[df][j] = O[d=df*16+g*4+j][myq]
  #pragma unroll
  for (int i = 0; i < 8; ++i) oacc[i] = (f32x4){0.f, 0.f, 0.f, 0.f};
  float mrun = -3e38f, lrun = 0.f;

  const int rk = t >> 4;
  const int kcol = (((t & 15) << 4) ^ ((rk & 15) << 4)) >> 1;  // d offset (elems)
  const int rv = t >> 3;
  const int vcol = (((t & 7) << 4) ^ ((rv & 7) << 4)) >> 1;    // kv offset (elems)
  const F16* kBase = Km + (size_t)rk * E + h * 128 + kcol;
  const F16* vBase = Vt + (size_t)(h * 128 + rv) * S + vcol;
  F16* myP = (F16*)sP[w];

  auto stage = [&](int kt, int b) {
    const F16* kSrc = kBase + (size_t)kt * 64 * E;
    const F16* vSrc = vBase + kt * 64;
    #pragma unroll
    for (int it = 0; it < 4; ++it) {
      gload16(kSrc + (size_t)it * 16 * E, &sK[b][t * 8 + it * 2048]);
      gload16(vSrc + (size_t)it * 32 * S, &sV[b][t * 8 + it * 2048]);
    }
  };

  stage(0, 0);
  const int nt = qt + 1;

  for (int kt = 0; kt < nt; ++kt) {
    __syncthreads();  // tile kt landed; all waves done with buf being overwritten
    if (kt + 1 < nt) stage(kt + 1, (kt + 1) & 1);
    const char* bK = (const char*)sK[kt & 1];
    const char* bV = (const char*)sV[kt & 1];

    // ---- QK^T swapped: sacc[ni][j] = S[kv=kt*64+ni*16+g*4+j][myq] ----
    f32x4 sacc[4];
    #pragma unroll
    for (int i = 0; i < 4; ++i) sacc[i] = (f32x4){0.f, 0.f, 0.f, 0.f};
    __builtin_amdgcn_s_setprio(1);
    #pragma unroll
    for (int kd = 0; kd < 4; ++kd) {
      const int kb = kd * 64 + (g << 4);
      #pragma unroll
      for (int ni = 0; ni < 4; ++ni) {
        const int rn = ni * 16 + (lane & 15);
        half8 kf = *(const half8*)(bK + rn * 256 + (kb ^ ((rn & 15) << 4)));
        sacc[ni] = __builtin_amdgcn_mfma_f32_16x16x32_f16(kf, qf[kd], sacc[ni], 0, 0, 0);
      }
    }
    __builtin_amdgcn_s_setprio(0);

    // ---- mask + in-register row max (one q per lane) ----
    const bool diag = (kt == nt - 1);
    const int kv0 = kt * 64 + g * 4;
    float mx = -3e38f;
    #pragma unroll
    for (int ni = 0; ni < 4; ++ni) {
      #pragma unroll
      for (int j = 0; j < 4; ++j) {
        float s = sacc[ni][j];
        if (diag && (kv0 + ni * 16 + j) > myq) s += MASK_SC;
        sacc[ni][j] = s;
        mx = fmaxf(mx, s);
      }
    }
    mx = fmaxf(mx, __shfl_xor(mx, 16));
    mx = fmaxf(mx, __shfl_xor(mx, 32));

    // ---- online softmax with defer-max (THR=8) ----
    if (__any(mx > mrun + 8.0f)) {
      const float mnew = fmaxf(mrun, mx);
      const float sc = __expf(mrun - mnew);
      float rs = 0.f;
      #pragma unroll
      for (int ni = 0; ni < 4; ++ni)
        #pragma unroll
        for (int j = 0; j < 4; ++j) {
          const float p = __expf(sacc[ni][j] - mnew);
          sacc[ni][j] = p;
          rs += p;
        }
      rs += __shfl_xor(rs, 16);
      rs += __shfl_xor(rs, 32);
      lrun = lrun * sc + rs;
      mrun = mnew;
      #pragma unroll
      for (int df = 0; df < 8; ++df)
        #pragma unroll
        for (int j = 0; j < 4; ++j) oacc[df][j] *= sc;
    } else {
      float rs = 0.f;
      #pragma unroll
      for (int ni = 0; ni < 4; ++ni)
        #pragma unroll
        for (int j = 0; j < 4; ++j) {
          const float p = __expf(sacc[ni][j] - mrun);  // bounded by e^8
          sacc[ni][j] = p;
          rs += p;
        }
      rs += __shfl_xor(rs, 16);
      rs += __shfl_xor(rs, 32);
      lrun += rs;
    }

    // ---- P -> sP[q][kv] (8B stores, j-contiguous kv), wave-private ----
    {
      char* rowp = (char*)myP + (lane & 15) * 128;
      const int swz = ((lane & 15) & 7) << 4;
      #pragma unroll
      for (int ni = 0; ni < 4; ++ni) {
        half4 pk;
        #pragma unroll
        for (int j = 0; j < 4; ++j) pk[j] = (F16)sacc[ni][j];
        *(half4*)(rowp + ((ni * 32 + g * 8) ^ swz)) = pk;
      }
    }

    // ---- PV swapped: oacc[df] = mfma(V_frag, P_frag) -> O^T ----
    __builtin_amdgcn_s_setprio(1);
    #pragma unroll
    for (int kk = 0; kk < 2; ++kk) {
      const int kb = kk * 64 + (g << 4);
      const int ra = lane & 15;
      half8 pa = *(const half8*)((const char*)myP + ra * 128 + (kb ^ ((ra & 7) << 4)));
      #pragma unroll
      for (int df = 0; df < 8; ++df) {
        const int rd = df * 16 + (lane & 15);
        half8 vf = *(const half8*)(bV + rd * 128 + (kb ^ ((rd & 7) << 4)));
        oacc[df] = __builtin_amdgcn_mfma_f32_16x16x32_f16(vf, pa, oacc[df], 0, 0, 0);
      }
    }
    __builtin_amdgcn_s_setprio(0);
  }

  // ---- epilogue: O[myq][h*128 + df*16 + g*4 + j] ----
  const float inv = 1.0f / lrun;
  F16* orow = O + (size_t)myq * E + h * 128;
  #pragma unroll
  for (int df = 0; df < 8; ++df) {
    half4 ov;
    #pragma unroll
    for (int j = 0; j < 4; ++j) ov[j] = (F16)(oacc[df][j] * inv);
    *(half4*)(orow + df * 16 + g * 4) = ov;
  }
}

// ---------------- launcher ----------------
extern "C" void kernel_launch(void* const* d_in, const int* in_sizes, int n_in,
                              void* d_out, int out_size, void* d_ws, size_t ws_size,
                              hipStream_t stream) {
  const float* X  = (const float*)d_in[0];
  const float* Wq = (const float*)d_in[1];
  const float* Wk = (const float*)d_in[2];
  const float* Wv = (const float*)d_in[3];
  const float* Wo = (const float*)d_in[4];
  float* out = (float*)d_out;

  const size_t MAT = (size_t)2048 * 2048;
  F16* Xh  = (F16*)d_ws;     // X f16 [S,E]; later reused as attn output Ah
  F16* Wt0 = Xh + MAT;       // Wq^T, then Wv^T
  F16* Wt1 = Wt0 + MAT;      // Wk^T, then Wo^T
  F16* Qh  = Wt1 + MAT;      // Q (pre-scaled by 1/sqrt(D))
  F16* Kh  = Qh + MAT;       // K
  F16* Vh  = Kh + MAT;       // V^T [E,S]
  // workspace: 6 * 8 MiB = 48 MiB

  dim3 b256(256);
  cast_f32_f16_k<<<dim3(MAT / 2048), b256, 0, stream>>>(X, Xh);

  transpose_cast2_k<<<dim3(32, 32, 2), b256, 0, stream>>>(Wq, Wk, Wt0, Wt1);
  gemm_bt_k<1><<<dim3(32, 32), b256, 0, stream>>>(Xh, Wt0, Qh, Kh);   // Q (scaled), K

  transpose_cast2_k<<<dim3(32, 32, 2), b256, 0, stream>>>(Wv, Wo, Wt0, Wt1);
  gemm_bt_k<0><<<dim3(16, 32), b256, 0, stream>>>(Wt0, Xh, Vh, nullptr);  // V^T = Wv^T X^T

  attn_fwd_k<<<dim3(512), b256, 0, stream>>>(Qh, Kh, Vh, Xh);  // attn out -> Xh

  gemm_bt_k<2><<<dim3(16, 32), b256, 0, stream>>>(Xh, Wt1, out, nullptr);
}